// Round 1
// baseline (272.100 us; speedup 1.0000x reference)
//
#include <hip/hip_runtime.h>
#include <hip/hip_bf16.h>
#include <stdint.h>

// EuclideanDeconf: x[B,D] fp32, W[C,D] fp32 -> out[B,C] fp32
// out = (2/D)*x.W^T - ||x||^2/D - ||w||^2/D
#define B_ROWS 16384
#define D_DIM  1024
#define C_DIM  2048
#define KT32   (D_DIM / 32)    // 32 pack chunks (K=32) per tile-row
#define KT     (D_DIM / 64)    // 16 gemm K-tiles (BK=64)
#define MT_TOT (B_ROWS / 16)   // 1024 m-tiles
#define NT_TOT (C_DIM  / 16)   // 128  n-tiles

typedef short bf16x8 __attribute__((ext_vector_type(8)));   // 8 bf16 = 4 VGPRs
typedef float f32x4  __attribute__((ext_vector_type(4)));

#define AS1 __attribute__((address_space(1)))
#define AS3 __attribute__((address_space(3)))
#define BARRIER __builtin_amdgcn_s_barrier()
#define LGKM0 asm volatile("s_waitcnt lgkmcnt(0)")
#define VMCNT(n) asm volatile("s_waitcnt vmcnt(" #n ")" ::: "memory")
#define PRIO1 __builtin_amdgcn_s_setprio(1)
#define PRIO0 __builtin_amdgcn_s_setprio(0)

// ---------------------------------------------------------------------------
// pack_norm (verified R3, unchanged): fp32 -> bf16 in MFMA fragment order.
// Chunk (tile, ktc) = 1 KB = 64 lanes x 16 B; lane l holds row = tile*16+(l&15),
// k = ktc*32 + (l>>4)*8 .. +7 — exact A/B operand layout of
// mfma_f32_16x16x32_bf16. One wave per chunk; norms via atomicAdd.
// ---------------------------------------------------------------------------
__global__ __launch_bounds__(256) void pack_norm(
        const float* __restrict__ x, const float* __restrict__ W,
        ushort* __restrict__ Apk, ushort* __restrict__ Bpk,
        float* __restrict__ x2, float* __restrict__ w2) {
    int chunk = blockIdx.x * 4 + (threadIdx.x >> 6);
    const int lane = threadIdx.x & 63;
    const int XCH = MT_TOT * KT32;              // 32768 x-chunks
    const float* src; ushort* dst; float* norm;
    if (chunk < XCH) { src = x; dst = Apk; norm = x2; }
    else             { src = W; dst = Bpk; norm = w2; chunk -= XCH; }
    const int tile = chunk >> 5;                // /KT32
    const int kt   = chunk & 31;

    const int row = tile * 16 + (lane & 15);
    const int k0  = kt * 32 + (lane >> 4) * 8;
    const float4 v0 = *(const float4*)(src + (size_t)row * D_DIM + k0);
    const float4 v1 = *(const float4*)(src + (size_t)row * D_DIM + k0 + 4);
    float s = v0.x*v0.x + v0.y*v0.y + v0.z*v0.z + v0.w*v0.w
            + v1.x*v1.x + v1.y*v1.y + v1.z*v1.z + v1.w*v1.w;

    ushort u[8]; __hip_bfloat16 h;
    h = __float2bfloat16(v0.x); u[0] = *(const ushort*)&h;
    h = __float2bfloat16(v0.y); u[1] = *(const ushort*)&h;
    h = __float2bfloat16(v0.z); u[2] = *(const ushort*)&h;
    h = __float2bfloat16(v0.w); u[3] = *(const ushort*)&h;
    h = __float2bfloat16(v1.x); u[4] = *(const ushort*)&h;
    h = __float2bfloat16(v1.y); u[5] = *(const ushort*)&h;
    h = __float2bfloat16(v1.z); u[6] = *(const ushort*)&h;
    h = __float2bfloat16(v1.w); u[7] = *(const ushort*)&h;
    *(bf16x8*)(dst + ((size_t)chunk * 64 + lane) * 8) = *(const bf16x8*)u;

    s += __shfl_xor(s, 16, 64);
    s += __shfl_xor(s, 32, 64);
    if (lane < 16) atomicAdd(norm + tile * 16 + lane, s * (1.0f / (float)D_DIM));
}

// ---------------------------------------------------------------------------
// gemm_8ph (R4): 256x256 tile, 8 waves (2M x 4N, 128x64 per wave), BK=64,
// double-buffered 128 KiB LDS, 4-phase-per-K-tile schedule with counted
// vmcnt(8) (never drained to 0 in the main loop) + setprio(1) around each
// 16-MFMA cluster. Phases split by k-slice (ks) so each LDS half frees
// mid-K-tile -> 12 chunks in flight per wave (3 halves ahead).
//   P0: ds_read B[*,ks0]+A[mi0-3,ks0] | stage 2 A-chunks (kt+1,h1) | 16 MFMA
//   P1: ds_read A[mi4-7,ks0]          | stage 2 B-chunks (kt+1,h1) | vm(8) | 16 MFMA
//   P2: ds_read B[*,ks1]+A[mi0-3,ks1] | stage 2 A-chunks (kt+2,h0) | 16 MFMA
//   P3: ds_read A[mi4-7,ks1]          | stage 2 B-chunks (kt+2,h0) | vm(8) | 16 MFMA
// Tail kept uniform by staging wrapped (harmless) chunks into dead regions.
// Chunks are fragment-ordered 1 KB (lane*16B) -> conflict-free ds_read_b128,
// and global_load_lds staging is linear (wave-uniform base + lane*16).
// ---------------------------------------------------------------------------
__global__ __launch_bounds__(512, 2) void gemm_8ph(
        const ushort* __restrict__ Apk, const ushort* __restrict__ Bpk,
        const float* __restrict__ x2, const float* __restrict__ w2,
        float* __restrict__ out) {
    __shared__ ushort As[32768];   // 64 KB: 2 bufs x 16 tiles x 2 ks x 512
    __shared__ ushort Bs[32768];   // 64 KB

    const int tid  = threadIdx.x;
    const int lane = tid & 63;
    const int wv   = tid >> 6;          // [0,8)
    const int wm   = wv >> 2;           // [0,2)
    const int wn   = wv & 3;            // [0,4)

    // bijective XCD swizzle: 512 blocks, 64 per XCD; blocks sharing an
    // A-panel (same bm, bn 0..7) are wid-consecutive -> same XCD L2.
    const int wid = (blockIdx.x & 7) * 64 + (blockIdx.x >> 3);
    const int bm  = wid >> 3;           // [0,64)
    const int bn  = wid & 7;            // [0,8)

    const ushort* aSrc = Apk + (size_t)bm * 16 * KT32 * 512 + lane * 8;
    const ushort* bSrc = Bpk + (size_t)bn * 16 * KT32 * 512 + lane * 8;
    const ushort* aRd  = As + wm * 8192 + lane * 8;   // wave's 8 A tiles
    const ushort* bRd  = Bs + wn * 4096 + lane * 8;   // wave's 4 B tiles

    const int mt0 = wv * 2, mt1 = wv * 2 + 1;         // staged tiles (A and B)

#define STA(mt, ktc, ldsOff) __builtin_amdgcn_global_load_lds( \
        (const AS1 void*)(aSrc + ((size_t)(mt) * KT32 + (ktc)) * 512), \
        (AS3 void*)(As + (ldsOff)), 16, 0, 0)
#define STB(nt, ktc, ldsOff) __builtin_amdgcn_global_load_lds( \
        (const AS1 void*)(bSrc + ((size_t)(nt) * KT32 + (ktc)) * 512), \
        (AS3 void*)(Bs + (ldsOff)), 16, 0, 0)
#define LDA(bo, mi, ks) (*(const bf16x8*)(aRd + (bo) + (mi) * 1024 + (ks) * 512))
#define LDB(bo, ni, ks) (*(const bf16x8*)(bRd + (bo) + (ni) * 1024 + (ks) * 512))
#define MFMA4(av, mi) \
    acc[mi][0] = __builtin_amdgcn_mfma_f32_16x16x32_bf16(av, b0, acc[mi][0], 0, 0, 0); \
    acc[mi][1] = __builtin_amdgcn_mfma_f32_16x16x32_bf16(av, b1, acc[mi][1], 0, 0, 0); \
    acc[mi][2] = __builtin_amdgcn_mfma_f32_16x16x32_bf16(av, b2, acc[mi][2], 0, 0, 0); \
    acc[mi][3] = __builtin_amdgcn_mfma_f32_16x16x32_bf16(av, b3, acc[mi][3], 0, 0, 0)

    f32x4 acc[8][4];
    #pragma unroll
    for (int mi = 0; mi < 8; ++mi)
        #pragma unroll
        for (int ni = 0; ni < 4; ++ni)
            acc[mi][ni] = (f32x4){0.f, 0.f, 0.f, 0.f};

    // ---- prologue: stage (kt0,h0), (kt0,h1), (kt1,h0) = 12 chunks/wave ----
    STA(mt0, 0, mt0 * 1024);              STA(mt1, 0, mt1 * 1024);
    STB(mt0, 0, mt0 * 1024);              STB(mt1, 0, mt1 * 1024);
    STA(mt0, 1, mt0 * 1024 + 512);        STA(mt1, 1, mt1 * 1024 + 512);
    STB(mt0, 1, mt0 * 1024 + 512);        STB(mt1, 1, mt1 * 1024 + 512);
    STA(mt0, 2, 16384 + mt0 * 1024);      STA(mt1, 2, 16384 + mt1 * 1024);
    STB(mt0, 2, 16384 + mt0 * 1024);      STB(mt1, 2, 16384 + mt1 * 1024);
    VMCNT(8);   // (kt0,h0) landed; (kt0,h1)+(kt1,h0) = 8 still in flight
    BARRIER;

    #pragma unroll 2
    for (int kt = 0; kt < KT; ++kt) {
        const int bo  = (kt & 1) * 16384;
        const int nbo = bo ^ 16384;
        const int kc1 = ((kt + 1) * 2 + 1) & 31;  // (kt+1, ks1) pack chunk
        const int kc2 = ((kt + 2) * 2) & 31;      // (kt+2, ks0) pack chunk
        bf16x8 a0, a1, a2, a3, b0, b1, b2, b3;

        // ---- P0: ks0, mi 0-3 ----
        b0 = LDB(bo, 0, 0); b1 = LDB(bo, 1, 0); b2 = LDB(bo, 2, 0); b3 = LDB(bo, 3, 0);
        a0 = LDA(bo, 0, 0); a1 = LDA(bo, 1, 0); a2 = LDA(bo, 2, 0); a3 = LDA(bo, 3, 0);
        STA(mt0, kc1, nbo + mt0 * 1024 + 512);
        STA(mt1, kc1, nbo + mt1 * 1024 + 512);
        BARRIER; LGKM0; PRIO1;
        MFMA4(a0, 0); MFMA4(a1, 1); MFMA4(a2, 2); MFMA4(a3, 3);
        PRIO0; BARRIER;

        // ---- P1: ks0, mi 4-7 ----
        a0 = LDA(bo, 4, 0); a1 = LDA(bo, 5, 0); a2 = LDA(bo, 6, 0); a3 = LDA(bo, 7, 0);
        STB(mt0, kc1, nbo + mt0 * 1024 + 512);
        STB(mt1, kc1, nbo + mt1 * 1024 + 512);
        VMCNT(8);   // (kt,h1) landed for P2; 8 newer chunks stay in flight
        BARRIER; LGKM0; PRIO1;
        MFMA4(a0, 4); MFMA4(a1, 5); MFMA4(a2, 6); MFMA4(a3, 7);
        PRIO0; BARRIER;

        // ---- P2: ks1, mi 0-3 (h0 of buf now free -> stage (kt+2,h0)) ----
        b0 = LDB(bo, 0, 1); b1 = LDB(bo, 1, 1); b2 = LDB(bo, 2, 1); b3 = LDB(bo, 3, 1);
        a0 = LDA(bo, 0, 1); a1 = LDA(bo, 1, 1); a2 = LDA(bo, 2, 1); a3 = LDA(bo, 3, 1);
        STA(mt0, kc2, bo + mt0 * 1024);
        STA(mt1, kc2, bo + mt1 * 1024);
        BARRIER; LGKM0; PRIO1;
        MFMA4(a0, 0); MFMA4(a1, 1); MFMA4(a2, 2); MFMA4(a3, 3);
        PRIO0; BARRIER;

        // ---- P3: ks1, mi 4-7 ----
        a0 = LDA(bo, 4, 1); a1 = LDA(bo, 5, 1); a2 = LDA(bo, 6, 1); a3 = LDA(bo, 7, 1);
        STB(mt0, kc2, bo + mt0 * 1024);
        STB(mt1, kc2, bo + mt1 * 1024);
        VMCNT(8);   // (kt+1,h0) landed for next P0; 8 newer stay in flight
        BARRIER; LGKM0; PRIO1;
        MFMA4(a0, 4); MFMA4(a1, 5); MFMA4(a2, 6); MFMA4(a3, 7);
        PRIO0; BARRIER;
    }

    // ---- epilogue: C/D layout col=lane&15, row=(lane>>4)*4+reg (m89) ----
    const float scale = 2.0f / (float)D_DIM;
    const int rsel = lane & 15;
    const int quad = lane >> 4;
    const int row0 = bm * 256 + wm * 128 + quad * 4;
    const int col0 = bn * 256 + wn * 64 + rsel;

    float w2c[4];
    #pragma unroll
    for (int ni = 0; ni < 4; ++ni) w2c[ni] = w2[col0 + ni * 16];

    #pragma unroll
    for (int mi = 0; mi < 8; ++mi) {
        const int rbase = row0 + mi * 16;
        float xr[4];
        #pragma unroll
        for (int r = 0; r < 4; ++r) xr[r] = x2[rbase + r];
        #pragma unroll
        for (int ni = 0; ni < 4; ++ni) {
            const int c = col0 + ni * 16;
            #pragma unroll
            for (int r = 0; r < 4; ++r)
                out[(size_t)(rbase + r) * C_DIM + c] =
                    acc[mi][ni][r] * scale - xr[r] - w2c[ni];
        }
    }
#undef STA
#undef STB
#undef LDA
#undef LDB
#undef MFMA4
}

// ---------------------------------------------------------------------------
extern "C" void kernel_launch(void* const* d_in, const int* in_sizes, int n_in,
                              void* d_out, int out_size, void* d_ws, size_t ws_size,
                              hipStream_t stream) {
    const float* x = (const float*)d_in[0];   // [B, D] fp32
    const float* W = (const float*)d_in[1];   // [C, D] fp32
    float* out = (float*)d_out;               // [B, C] fp32

    // ws: Apk (32 MB bf16 packed) | Bpk (4 MB) | x2 (64 KB) | w2 (8 KB)
    char* ws = (char*)d_ws;
    ushort* Apk = (ushort*)ws;
    ushort* Bpk = (ushort*)(ws + (size_t)B_ROWS * D_DIM * sizeof(ushort));
    float*  x2  = (float*)(ws + (size_t)(B_ROWS + C_DIM) * D_DIM * sizeof(ushort));
    float*  w2  = x2 + B_ROWS;

    hipMemsetAsync(x2, 0, (B_ROWS + C_DIM) * sizeof(float), stream);

    pack_norm<<<(MT_TOT * KT32 + NT_TOT * KT32) / 4, 256, 0, stream>>>(
        x, W, Apk, Bpk, x2, w2);

    gemm_8ph<<<(B_ROWS / 256) * (C_DIM / 256), 512, 0, stream>>>(
        Apk, Bpk, x2, w2, out);
}

// Round 2
// 245.758 us; speedup vs baseline: 1.1072x; 1.1072x over previous
//
#include <hip/hip_runtime.h>
#include <hip/hip_bf16.h>
#include <stdint.h>

// EuclideanDeconf: x[B,D] fp32, W[C,D] fp32 -> out[B,C] fp32
// out = (2/D)*x.W^T - ||x||^2/D - ||w||^2/D
#define B_ROWS 16384
#define D_DIM  1024
#define C_DIM  2048
#define KT32   (D_DIM / 32)    // 32 K-steps of 32 (= pack chunk granularity)
#define MT_TOT (B_ROWS / 16)   // 1024 m-tiles
#define NT_TOT (C_DIM  / 16)   // 128  n-tiles

typedef short bf16x8 __attribute__((ext_vector_type(8)));   // 8 bf16 = 4 VGPRs
typedef float f32x4  __attribute__((ext_vector_type(4)));

#define AS1 __attribute__((address_space(1)))
#define AS3 __attribute__((address_space(3)))
#define BARRIER __builtin_amdgcn_s_barrier()
#define LGKM0 asm volatile("s_waitcnt lgkmcnt(0)")
#define VMCNT(n) asm volatile("s_waitcnt vmcnt(" #n ")" ::: "memory")
#define PRIO1 __builtin_amdgcn_s_setprio(1)
#define PRIO0 __builtin_amdgcn_s_setprio(0)

// ---------------------------------------------------------------------------
// pack_norm (verified R3, unchanged): fp32 -> bf16 in MFMA fragment order.
// Chunk (tile, ktc) = 1 KB = 64 lanes x 16 B; lane l holds row = tile*16+(l&15),
// k = ktc*32 + (l>>4)*8 .. +7 — exact A/B operand layout of
// mfma_f32_16x16x32_bf16. One wave per chunk; norms via atomicAdd.
// ---------------------------------------------------------------------------
__global__ __launch_bounds__(256) void pack_norm(
        const float* __restrict__ x, const float* __restrict__ W,
        ushort* __restrict__ Apk, ushort* __restrict__ Bpk,
        float* __restrict__ x2, float* __restrict__ w2) {
    int chunk = blockIdx.x * 4 + (threadIdx.x >> 6);
    const int lane = threadIdx.x & 63;
    const int XCH = MT_TOT * KT32;              // 32768 x-chunks
    const float* src; ushort* dst; float* norm;
    if (chunk < XCH) { src = x; dst = Apk; norm = x2; }
    else             { src = W; dst = Bpk; norm = w2; chunk -= XCH; }
    const int tile = chunk >> 5;                // /KT32
    const int kt   = chunk & 31;

    const int row = tile * 16 + (lane & 15);
    const int k0  = kt * 32 + (lane >> 4) * 8;
    const float4 v0 = *(const float4*)(src + (size_t)row * D_DIM + k0);
    const float4 v1 = *(const float4*)(src + (size_t)row * D_DIM + k0 + 4);
    float s = v0.x*v0.x + v0.y*v0.y + v0.z*v0.z + v0.w*v0.w
            + v1.x*v1.x + v1.y*v1.y + v1.z*v1.z + v1.w*v1.w;

    ushort u[8]; __hip_bfloat16 h;
    h = __float2bfloat16(v0.x); u[0] = *(const ushort*)&h;
    h = __float2bfloat16(v0.y); u[1] = *(const ushort*)&h;
    h = __float2bfloat16(v0.z); u[2] = *(const ushort*)&h;
    h = __float2bfloat16(v0.w); u[3] = *(const ushort*)&h;
    h = __float2bfloat16(v1.x); u[4] = *(const ushort*)&h;
    h = __float2bfloat16(v1.y); u[5] = *(const ushort*)&h;
    h = __float2bfloat16(v1.z); u[6] = *(const ushort*)&h;
    h = __float2bfloat16(v1.w); u[7] = *(const ushort*)&h;
    *(bf16x8*)(dst + ((size_t)chunk * 64 + lane) * 8) = *(const bf16x8*)u;

    s += __shfl_xor(s, 16, 64);
    s += __shfl_xor(s, 32, 64);
    if (lane < 16) atomicAdd(norm + tile * 16 + lane, s * (1.0f / (float)D_DIM));
}

// ---------------------------------------------------------------------------
// gemm_tb (R5): 128x128 tile, 4 waves 2x2 (wave tile 64x64), BK=32,
// TRIPLE-buffered LDS (3 x 16 KB = 48 KB -> 3 blocks/CU, 12 waves/CU).
// Per phase (one K-step of 32):
//   8 x ds_read_b128 frags (conflict-free, 1 KB fragment-ordered chunks)
//   4 x global_load_lds: stage K-step kt+2 into the buffer freed at kt-1
//   s_waitcnt vmcnt(4)  <- counted: kt+1's chunks landed, kt+2's stay in flight
//   s_barrier; lgkmcnt(0); setprio(1); 16 MFMA; setprio(0); s_barrier
// vmcnt never drains to 0 in the loop (T4); the wait targets chunks issued a
// full phase earlier (> HBM latency). Cross-block TLP (3 blocks/CU) hides
// barrier stalls and the epilogue (the R4 1-block/CU regression's lesson).
// Tail: (kt+2)&31 stages harmless wrapped chunks into never-read buffers.
// XCD slab remap for A-panel L2 locality (R2).
// Epilogue: out = acc*(2/D) - x2[row] - w2[col]  (C/D layout per m89).
// ---------------------------------------------------------------------------
__global__ __launch_bounds__(256, 3) void gemm_tb(
        const ushort* __restrict__ Apk, const ushort* __restrict__ Bpk,
        const float* __restrict__ x2, const float* __restrict__ w2,
        float* __restrict__ out) {
    __shared__ ushort As[3 * 4096];   // 24 KB: 3 bufs x 8 tiles x 512
    __shared__ ushort Bs[3 * 4096];   // 24 KB

    const int tid  = threadIdx.x;
    const int lane = tid & 63;
    const int wv   = tid >> 6;          // [0,4)

    const int wid = (blockIdx.x & 7) * 256 + (blockIdx.x >> 3);  // XCD slab
    const int bm  = wid >> 4;           // [0,128)
    const int bn  = wid & 15;           // [0,16)

    // staging source bases (ushort units); chunk (tile,ktc) at (tile*KT32+ktc)*512
    const ushort* aSrc = Apk + ((size_t)(bm * 8) * KT32) * 512 + lane * 8;
    const ushort* bSrc = Bpk + ((size_t)(bn * 8) * KT32) * 512 + lane * 8;

    // fragment-read bases (add rotating buffer offset + mi*512 imm at use)
    const ushort* aRd = As + (wv >> 1) * 2048 + lane * 8;   // tiles (wv>>1)*4+mi
    const ushort* bRd = Bs + (wv & 1) * 2048 + lane * 8;    // tiles (wv&1)*4+ni

    // each wave stages A tiles {wv, wv+4} and B tiles {wv, wv+4}
    const int t0 = wv, t1 = wv + 4;

#define STAGE(ktc, bufO) do { \
    __builtin_amdgcn_global_load_lds( \
        (const AS1 void*)(aSrc + ((size_t)t0 * KT32 + (ktc)) * 512), \
        (AS3 void*)(As + (bufO) + t0 * 512), 16, 0, 0); \
    __builtin_amdgcn_global_load_lds( \
        (const AS1 void*)(aSrc + ((size_t)t1 * KT32 + (ktc)) * 512), \
        (AS3 void*)(As + (bufO) + t1 * 512), 16, 0, 0); \
    __builtin_amdgcn_global_load_lds( \
        (const AS1 void*)(bSrc + ((size_t)t0 * KT32 + (ktc)) * 512), \
        (AS3 void*)(Bs + (bufO) + t0 * 512), 16, 0, 0); \
    __builtin_amdgcn_global_load_lds( \
        (const AS1 void*)(bSrc + ((size_t)t1 * KT32 + (ktc)) * 512), \
        (AS3 void*)(Bs + (bufO) + t1 * 512), 16, 0, 0); \
  } while (0)

    f32x4 acc[4][4];
    #pragma unroll
    for (int mi = 0; mi < 4; ++mi)
        #pragma unroll
        for (int ni = 0; ni < 4; ++ni)
            acc[mi][ni] = (f32x4){0.f, 0.f, 0.f, 0.f};

    // ---- prologue: stage kt=0 -> buf0, kt=1 -> buf1 (8 loads in flight) ----
    STAGE(0, 0);
    STAGE(1, 4096);
    VMCNT(4);        // kt=0's 4 chunks landed; kt=1's 4 stay in flight
    BARRIER;

    int curO = 0, nxtO = 4096, stgO = 8192;   // rotating buffer offsets
    for (int kt = 0; kt < KT32; ++kt) {
        bf16x8 a[4], b[4];
        #pragma unroll
        for (int mi = 0; mi < 4; ++mi)
            a[mi] = *(const bf16x8*)(aRd + curO + mi * 512);
        #pragma unroll
        for (int ni = 0; ni < 4; ++ni)
            b[ni] = *(const bf16x8*)(bRd + curO + ni * 512);

        STAGE((kt + 2) & 31, stgO);   // into buffer freed at kt-1

        VMCNT(4);    // kt+1's 4 landed (issued one full phase ago); 4 in flight
        BARRIER;     // all waves' kt+1 chunks visible -> next phase safe
        LGKM0;
        PRIO1;
        #pragma unroll
        for (int mi = 0; mi < 4; ++mi)
            #pragma unroll
            for (int ni = 0; ni < 4; ++ni)
                acc[mi][ni] = __builtin_amdgcn_mfma_f32_16x16x32_bf16(
                    a[mi], b[ni], acc[mi][ni], 0, 0, 0);
        PRIO0;
        BARRIER;     // reads of buf(cur) done before anyone stages into it

        const int t = curO; curO = nxtO; nxtO = stgO; stgO = t;
    }

    // ---- epilogue: C/D layout col=lane&15, row=(lane>>4)*4+reg (m89) ----
    const float scale = 2.0f / (float)D_DIM;
    const int rsel = lane & 15;
    const int quad = lane >> 4;
    const int mT0  = bm * 8 + (wv >> 1) * 4;
    const int nT0  = bn * 8 + (wv & 1) * 4;
    const int row0 = mT0 * 16 + quad * 4;
    const int col0 = nT0 * 16 + rsel;

    float x2r[4][4];
    #pragma unroll
    for (int mi = 0; mi < 4; ++mi)
        #pragma unroll
        for (int r = 0; r < 4; ++r)
            x2r[mi][r] = x2[row0 + mi * 16 + r];

    #pragma unroll
    for (int ni = 0; ni < 4; ++ni) {
        const int c = col0 + ni * 16;
        const float wc = w2[c];
        #pragma unroll
        for (int mi = 0; mi < 4; ++mi) {
            #pragma unroll
            for (int r = 0; r < 4; ++r) {
                const int rr = row0 + mi * 16 + r;
                out[(size_t)rr * C_DIM + c] = acc[mi][ni][r] * scale - x2r[mi][r] - wc;
            }
        }
    }
#undef STAGE
}

// ---------------------------------------------------------------------------
extern "C" void kernel_launch(void* const* d_in, const int* in_sizes, int n_in,
                              void* d_out, int out_size, void* d_ws, size_t ws_size,
                              hipStream_t stream) {
    const float* x = (const float*)d_in[0];   // [B, D] fp32
    const float* W = (const float*)d_in[1];   // [C, D] fp32
    float* out = (float*)d_out;               // [B, C] fp32

    // ws: Apk (32 MB bf16 packed) | Bpk (4 MB) | x2 (64 KB) | w2 (8 KB)
    char* ws = (char*)d_ws;
    ushort* Apk = (ushort*)ws;
    ushort* Bpk = (ushort*)(ws + (size_t)B_ROWS * D_DIM * sizeof(ushort));
    float*  x2  = (float*)(ws + (size_t)(B_ROWS + C_DIM) * D_DIM * sizeof(ushort));
    float*  w2  = x2 + B_ROWS;

    hipMemsetAsync(x2, 0, (B_ROWS + C_DIM) * sizeof(float), stream);

    pack_norm<<<(MT_TOT * KT32 + NT_TOT * KT32) / 4, 256, 0, stream>>>(
        x, W, Apk, Bpk, x2, w2);

    gemm_tb<<<(B_ROWS / 128) * (C_DIM / 128), 256, 0, stream>>>(
        Apk, Bpk, x2, w2, out);
}